// Round 19
// baseline (96.518 us; speedup 1.0000x reference)
//
#include <hip/hip_runtime.h>
#include <stdint.h>

#define Bb 8
#define Nn 1024
#define Dd 768
#define Hh 12
#define HDd 64
#define Mm (Bb * Nn)      // 8192
#define QKVN (3 * Dd)     // 2304
#define SCALE_F 8.0f      // sqrt(64), multiplies (no softmax in reference)

typedef __attribute__((ext_vector_type(8))) short bf16x8;
typedef __attribute__((ext_vector_type(4))) float f32x4;

__device__ __forceinline__ float bf2f(unsigned short u) {
  unsigned int v = ((unsigned int)u) << 16;
  float f;
  __builtin_memcpy(&f, &v, 4);
  return f;
}
__device__ __forceinline__ unsigned short f2bf(float f) {
  unsigned int u;
  __builtin_memcpy(&u, &f, 4);
  u += 0x7FFFu + ((u >> 16) & 1u);  // round-to-nearest-even
  return (unsigned short)(u >> 16);
}

#define GLDS16(g, l)                                                          \
  __builtin_amdgcn_global_load_lds(                                          \
      (const __attribute__((address_space(1))) void*)(g),                    \
      (__attribute__((address_space(3))) void*)(l), 16, 0, 0)

// ---------------- f32 -> bf16 convert (x, w_qkv, w_fc) ----------------
__global__ void convert_kernel(const float* __restrict__ x,
                               const float* __restrict__ wqkv,
                               const float* __restrict__ wfc,
                               unsigned short* __restrict__ xb,
                               unsigned short* __restrict__ wqkvb,
                               unsigned short* __restrict__ wfcb) {
  const int n1 = Mm * Dd / 4, n2 = QKVN * Dd / 4, n3 = Dd * Dd / 4;
  const int total = n1 + n2 + n3;
  for (int i = blockIdx.x * blockDim.x + threadIdx.x; i < total;
       i += gridDim.x * blockDim.x) {
    const float* src;
    unsigned short* dst;
    int j;
    if (i < n1) {
      src = x; dst = xb; j = i;
    } else if (i < n1 + n2) {
      src = wqkv; dst = wqkvb; j = i - n1;
    } else {
      src = wfc; dst = wfcb; j = i - n1 - n2;
    }
    const float4 v = ((const float4*)src)[j];
    ushort4 o;
    o.x = f2bf(v.x); o.y = f2bf(v.y); o.z = f2bf(v.z); o.w = f2bf(v.w);
    ((ushort4*)dst)[j] = o;
  }
}

// -------- BMxBN GEMM: C = A * B^T (+bias) -----------------------------
// BK=64; NW waves (NW*64 threads) as (BM/64 or 1)(m) x (BN/64)(n) wave
// grid; wave tile 64x64 (acc[4][4], the R12-proven per-wave codegen).
// XOR-swizzle via pre-swizzled global source (0 conflicts verified).
// DBUF=false: single-buffer 2-barrier loop — BEST for the big GEMM
//   (R17: DBUF's 2 blk/CU residency loss cancels its overlap gain).
// DBUF=true: T3-minimum double-buffer — for latency-chain-bound small
//   GEMMs at low block count (R15 win on fc GEMM).
// launch_bounds min-waves kept low: R8 showed tight VGPR caps spill acc.
// Requires gridDim.x*y*z % 8 == 0 (bijective chunked XCD remap).
template <int BM, int BN, int NW, bool BF16OUT, bool DBUF>
__global__ __launch_bounds__(NW * 64, NW == 4 ? 4 : 2) void gemmk(
    const unsigned short* __restrict__ A, int lda, size_t aBatch,
    const unsigned short* __restrict__ Bm, int ldb, size_t bBatch,
    void* __restrict__ Cout, int ldc, size_t cBatch,
    const float* __restrict__ bias, int K) {
  constexpr int NWC = BN / 64;          // n-waves
  constexpr int MI = 4, NI = 4;         // 64x64 wave tile
  constexpr int ACHA = BM / 8 / NW;     // A staging chunks per wave
  constexpr int ACHB = BN / 8 / NW;     // B staging chunks per wave
  constexpr int NS = DBUF ? 2 : 1;
  __shared__ unsigned short lds[NS][(BM + BN) * 64];
  const int tid = threadIdx.x;
  const int lane = tid & 63, w = tid >> 6;

  // ---- bijective chunked XCD remap, x-fastest decode ----
  const int gx = gridDim.x, gy = gridDim.y;
  int lid = blockIdx.x + gx * (blockIdx.y + gy * blockIdx.z);
  const int nwg = gx * gy * (int)gridDim.z;
  const int qch = nwg >> 3;
  lid = (lid & 7) * qch + (lid >> 3);
  const int bx = lid % gx;
  const int rem = lid / gx;
  const int by = rem % gy;
  const int bz = rem / gy;

  const int m0 = by * BM, n0 = bx * BN;
  const unsigned short* Aptr = A + (size_t)bz * aBatch;
  const unsigned short* Bptr = Bm + (size_t)bz * bBatch;

  const int lr = lane >> 3, lc = lane & 7;
  const int csw = (lc ^ lr) << 3;  // inverse-swizzled source col (elems)
  const int wr = w / NWC, wc = w % NWC;
  const int fr = lane & 15, fk = lane >> 4;
  const int nt = K >> 6;  // 12

  f32x4 acc[MI][NI] = {};

  auto stage = [&](int t, int s) {
    const int k0 = t << 6;
#pragma unroll
    for (int l = 0; l < ACHA; ++l) {
      const int c = w * ACHA + l;
      GLDS16(Aptr + (size_t)(m0 + c * 8 + lr) * lda + k0 + csw,
             &lds[s][c * 512]);
    }
#pragma unroll
    for (int l = 0; l < ACHB; ++l) {
      const int c = w * ACHB + l;
      GLDS16(Bptr + (size_t)(n0 + c * 8 + lr) * ldb + k0 + csw,
             &lds[s][BM * 64 + c * 512]);
    }
  };

  auto compute = [&](int s) {
#pragma unroll
    for (int ks = 0; ks < 2; ++ks) {
      bf16x8 af[MI], bf[NI];
#pragma unroll
      for (int mi = 0; mi < MI; ++mi) {
        const int row = wr * 64 + mi * 16 + fr;
        af[mi] = *(const bf16x8*)&lds[s][row * 64 +
                                         ((ks * 32 + fk * 8) ^
                                          ((row & 7) << 3))];
      }
#pragma unroll
      for (int ni = 0; ni < NI; ++ni) {
        const int row = wc * 64 + ni * 16 + fr;
        bf[ni] = *(const bf16x8*)&lds[s][BM * 64 + row * 64 +
                                         ((ks * 32 + fk * 8) ^
                                          ((row & 7) << 3))];
      }
      __builtin_amdgcn_s_setprio(1);
#pragma unroll
      for (int mi = 0; mi < MI; ++mi)
#pragma unroll
        for (int ni = 0; ni < NI; ++ni)
          acc[mi][ni] = __builtin_amdgcn_mfma_f32_16x16x32_bf16(
              af[mi], bf[ni], acc[mi][ni], 0, 0, 0);
      __builtin_amdgcn_s_setprio(0);
    }
  };

  if constexpr (DBUF) {
    stage(0, 0);
    __syncthreads();  // slot 0 resident
    for (int t = 0; t < nt; ++t) {
      const int s = t & 1;
      if (t + 1 < nt) stage(t + 1, s ^ 1);  // async prefetch, other slot
      compute(s);
      __syncthreads();  // drains prefetch; all reads of slot s done
    }
  } else {
    for (int t = 0; t < nt; ++t) {
      stage(t, 0);
      __syncthreads();  // tile resident
      compute(0);
      __syncthreads();  // reads done before next stage overwrites
    }
  }

  // ---- epilogue ----
#pragma unroll
  for (int mi = 0; mi < MI; ++mi) {
#pragma unroll
    for (int ni = 0; ni < NI; ++ni) {
      const int col = n0 + wc * 64 + ni * 16 + fr;
      float bv = 0.0f;
      if (!BF16OUT) bv = bias[col];
#pragma unroll
      for (int r = 0; r < 4; ++r) {
        const int row = m0 + wr * 64 + mi * 16 + fk * 4 + r;
        const float val = acc[mi][ni][r] + bv;
        if (BF16OUT)
          ((unsigned short*)Cout + (size_t)bz * cBatch)
              [(size_t)row * ldc + col] = f2bf(val);
        else
          ((float*)Cout + (size_t)bz * cBatch)
              [(size_t)row * ldc + col] = val;
      }
    }
  }
}

// -------- kTv partials: part[c][bh][e][d] = sum_{j in chunk c} v*k ------
// grid (chunk=8, bh=96), 256 threads. No atomics: each block owns its slab.
__global__ __launch_bounds__(256) void ktv_kernel(
    const unsigned short* __restrict__ qkv, float* __restrict__ part) {
  __shared__ unsigned short kls[128 * 64];
  __shared__ unsigned short vls[128 * 64];
  const int bh = blockIdx.y;
  const int bb = bh / Hh, h = bh % Hh;
  const int chunk = blockIdx.x;
  const int j0 = chunk * 128;
  const int tid = threadIdx.x, lane = tid & 63, w = tid >> 6;
  const size_t rowbase = (size_t)(bb * Nn + j0);
#pragma unroll
  for (int i = 0; i < 4; ++i) {
    const int c = w * 4 + i;
    const int row = c * 8 + (lane >> 3);
    const int col = (lane & 7) * 8;
    const size_t g = (rowbase + row) * QKVN + h * HDd + col;
    GLDS16(qkv + g + Dd, &kls[c * 512]);       // k slice
    GLDS16(qkv + g + 2 * Dd, &vls[c * 512]);   // v slice
  }
  asm volatile("s_waitcnt vmcnt(0)" ::: "memory");
  __syncthreads();

  const int e0 = (tid >> 4) * 4, d0 = (tid & 15) * 4;
  float acc[4][4] = {};
#pragma unroll 4
  for (int j = 0; j < 128; ++j) {
    const ushort4 kv = *(const ushort4*)&kls[j * 64 + d0];
    const ushort4 vv = *(const ushort4*)&vls[j * 64 + e0];
    const float kf[4] = {bf2f(kv.x), bf2f(kv.y), bf2f(kv.z), bf2f(kv.w)};
    const float vf[4] = {bf2f(vv.x), bf2f(vv.y), bf2f(vv.z), bf2f(vv.w)};
#pragma unroll
    for (int e = 0; e < 4; ++e)
#pragma unroll
      for (int d = 0; d < 4; ++d) acc[e][d] += vf[e] * kf[d];
  }
  float* outp = part + ((size_t)chunk * 96 + bh) * 4096;
#pragma unroll
  for (int e = 0; e < 4; ++e)
#pragma unroll
    for (int d = 0; d < 4; ++d)
      outp[(e0 + e) * HDd + (d0 + d)] = acc[e][d];
}

// ------- kfin[bh][e][d] = bf16(SCALE * sum_c part[c][bh][e][d]) --------
__global__ __launch_bounds__(256) void kfin_kernel(
    const float* __restrict__ part, unsigned short* __restrict__ kfin) {
  const int bh = blockIdx.x, tid = threadIdx.x;
  const float* kp = part + (size_t)bh * 4096;
  unsigned short* op = kfin + (size_t)bh * 4096;
  for (int i = tid * 4; i < 4096; i += 1024) {
    float4 s = {0.f, 0.f, 0.f, 0.f};
#pragma unroll
    for (int cc = 0; cc < 8; ++cc) {
      const float4 v = *(const float4*)&kp[(size_t)cc * 96 * 4096 + i];
      s.x += v.x; s.y += v.y; s.z += v.z; s.w += v.w;
    }
    ushort4 o;
    o.x = f2bf(s.x * SCALE_F); o.y = f2bf(s.y * SCALE_F);
    o.z = f2bf(s.z * SCALE_F); o.w = f2bf(s.w * SCALE_F);
    *(ushort4*)&op[i] = o;
  }
}

// ---- attn_out: ao[b,j,h*64+e] = sum_d q[b,j,h,d] * kfin[bh][e][d] -----
// Writes into qkv's dead v-slice (cols 1536..2303). grid (jt=8, bh=96).
// A=q staged with the proven XOR-swizzle path; B=kfin in padded LDS.
__global__ __launch_bounds__(256) void attn_out_kernel(
    unsigned short* qkv, const unsigned short* __restrict__ kfin) {
  __shared__ unsigned short qls[128 * 64];
  __shared__ unsigned short bs[64 * 72];  // [e][d], pad 72 (2-way = free)
  const int bh = blockIdx.y;
  const int bb = bh / Hh, h = bh % Hh;
  const int jt = blockIdx.x;
  const int tid = threadIdx.x, lane = tid & 63, w = tid >> 6;
  const int lr = lane >> 3, lc = lane & 7;
  const int csw = (lc ^ lr) << 3;
  const size_t rowbase = (size_t)(bb * Nn + jt * 128);
#pragma unroll
  for (int l = 0; l < 4; ++l) {
    const int c = w * 4 + l;
    GLDS16(qkv + (rowbase + c * 8 + lr) * QKVN + h * HDd + csw,
           &qls[c * 512]);
  }
  for (int i = tid * 8; i < 4096; i += 2048) {
    const int e = i >> 6, d = i & 63;
    *(bf16x8*)&bs[e * 72 + d] = *(const bf16x8*)&kfin[(size_t)bh * 4096 + i];
  }
  asm volatile("s_waitcnt vmcnt(0)" ::: "memory");
  __syncthreads();

  const int fr = lane & 15, fk = lane >> 4;
  f32x4 acc[2][4] = {};
#pragma unroll
  for (int ks = 0; ks < 2; ++ks) {
    bf16x8 af[2];
#pragma unroll
    for (int mi = 0; mi < 2; ++mi) {
      const int row = w * 32 + mi * 16 + fr;
      af[mi] = *(const bf16x8*)&qls[row * 64 +
                                    ((ks * 32 + fk * 8) ^ ((row & 7) << 3))];
    }
#pragma unroll
    for (int ni = 0; ni < 4; ++ni) {
      const bf16x8 bfr =
          *(const bf16x8*)&bs[(ni * 16 + fr) * 72 + ks * 32 + fk * 8];
#pragma unroll
      for (int mi = 0; mi < 2; ++mi)
        acc[mi][ni] = __builtin_amdgcn_mfma_f32_16x16x32_bf16(
            af[mi], bfr, acc[mi][ni], 0, 0, 0);
    }
  }
#pragma unroll
  for (int mi = 0; mi < 2; ++mi)
#pragma unroll
    for (int ni = 0; ni < 4; ++ni)
#pragma unroll
      for (int r = 0; r < 4; ++r) {
        const int row = jt * 128 + w * 32 + mi * 16 + fk * 4 + r;
        const int col = ni * 16 + fr;
        qkv[((size_t)bb * Nn + row) * QKVN + 2 * Dd + h * HDd + col] =
            f2bf(acc[mi][ni][r]);
      }
}

extern "C" void kernel_launch(void* const* d_in, const int* in_sizes, int n_in,
                              void* d_out, int out_size, void* d_ws,
                              size_t ws_size, hipStream_t stream) {
  const float* x = (const float*)d_in[0];
  const float* wqkv = (const float*)d_in[1];
  const float* wfc = (const float*)d_in[2];
  const float* bfc = (const float*)d_in[3];
  float* out = (float*)d_out;

  char* ws = (char*)d_ws;
  unsigned short* xb    = (unsigned short*)(ws);                // 12.6 MB
  float*          part  = (float*)(ws);      // aliases xb (dead after gemm1)
  unsigned short* wqkvb = (unsigned short*)(ws + 12582912);     // 3.5 MB
  unsigned short* wfcb  = (unsigned short*)(ws + 16121856);     // 1.2 MB
  unsigned short* qkv   = (unsigned short*)(ws + 17301504);     // 37.7 MB
  unsigned short* kfin  = (unsigned short*)(ws + 55050240);     // 0.79 MB
  // total used: 55,836,672 bytes

  convert_kernel<<<2112, 256, 0, stream>>>(x, wqkv, wfc, xb, wqkvb, wfcb);
  // qkv = x * wqkv^T : M=8192, N=2304, K=768  (grid 18*64 = 1152, %8==0)
  // single-buffer 4-wave 128x128 — measured best across nine variants
  gemmk<128, 128, 4, true, false>
      <<<dim3(QKVN / 128, Mm / 128, 1), 256, 0, stream>>>(
          xb, Dd, 0, wqkvb, Dd, 0, qkv, QKVN, 0, nullptr, Dd);
  // part[c][bh] = per-chunk K^T V partials (xb is dead; reuse its space)
  ktv_kernel<<<dim3(8, 96), 256, 0, stream>>>(qkv, part);
  // kfin = bf16(SCALE * sum_c part)
  kfin_kernel<<<96, 256, 0, stream>>>(part, kfin);
  // attn_out: q x kfin -> overwrite qkv's dead v-slice
  attn_out_kernel<<<dim3(8, 96), 256, 0, stream>>>(qkv, kfin);
  // out = ao * wfc^T + bias : M=8192, N=768, K=768, SHARED weights
  // BM=64, 2-wave, DBUF: grid 6*128 = 768 blocks (%8==0) -> 3 blocks/CU,
  // single dispatch round — latency-chain hidden by TLP + overlap
  gemmk<64, 128, 2, false, true>
      <<<dim3(Dd / 128, Mm / 64, 1), 128, 0, stream>>>(
          qkv + 2 * Dd, QKVN, 0, wfcb, Dd, 0, out, Dd, 0, bfc, Dd);
}

// Round 20
// 95.116 us; speedup vs baseline: 1.0147x; 1.0147x over previous
//
#include <hip/hip_runtime.h>
#include <stdint.h>

#define Bb 8
#define Nn 1024
#define Dd 768
#define Hh 12
#define HDd 64
#define Mm (Bb * Nn)      // 8192
#define QKVN (3 * Dd)     // 2304
#define SCALE_F 8.0f      // sqrt(64), multiplies (no softmax in reference)

typedef __attribute__((ext_vector_type(8))) short bf16x8;
typedef __attribute__((ext_vector_type(4))) float f32x4;

__device__ __forceinline__ float bf2f(unsigned short u) {
  unsigned int v = ((unsigned int)u) << 16;
  float f;
  __builtin_memcpy(&f, &v, 4);
  return f;
}
__device__ __forceinline__ unsigned short f2bf(float f) {
  unsigned int u;
  __builtin_memcpy(&u, &f, 4);
  u += 0x7FFFu + ((u >> 16) & 1u);  // round-to-nearest-even
  return (unsigned short)(u >> 16);
}

#define GLDS16(g, l)                                                          \
  __builtin_amdgcn_global_load_lds(                                          \
      (const __attribute__((address_space(1))) void*)(g),                    \
      (__attribute__((address_space(3))) void*)(l), 16, 0, 0)

// ---------------- f32 -> bf16 convert (x, w_qkv, w_fc) ----------------
__global__ void convert_kernel(const float* __restrict__ x,
                               const float* __restrict__ wqkv,
                               const float* __restrict__ wfc,
                               unsigned short* __restrict__ xb,
                               unsigned short* __restrict__ wqkvb,
                               unsigned short* __restrict__ wfcb) {
  const int n1 = Mm * Dd / 4, n2 = QKVN * Dd / 4, n3 = Dd * Dd / 4;
  const int total = n1 + n2 + n3;
  for (int i = blockIdx.x * blockDim.x + threadIdx.x; i < total;
       i += gridDim.x * blockDim.x) {
    const float* src;
    unsigned short* dst;
    int j;
    if (i < n1) {
      src = x; dst = xb; j = i;
    } else if (i < n1 + n2) {
      src = wqkv; dst = wqkvb; j = i - n1;
    } else {
      src = wfc; dst = wfcb; j = i - n1 - n2;
    }
    const float4 v = ((const float4*)src)[j];
    ushort4 o;
    o.x = f2bf(v.x); o.y = f2bf(v.y); o.z = f2bf(v.z); o.w = f2bf(v.w);
    ((ushort4*)dst)[j] = o;
  }
}

// -------- BMxBN GEMM: C = A * B^T (+bias) -----------------------------
// BK=64; NW waves (NW*64 threads) as 2(m) x (BN/64)(n); wave tile 64x64.
// XOR-swizzle via pre-swizzled global source (0 conflicts verified).
// DBUF=false: single-buffer 2-barrier loop — BEST for the big GEMM
//   (R17: DBUF's 2 blk/CU residency loss cancels its overlap gain).
// DBUF=true: T3-minimum double-buffer — best for the small fc GEMM
//   (R15 win; latency-chain bound at low block count).
// launch_bounds min-waves kept low: R8 showed tight VGPR caps spill acc.
// Requires gridDim.x*y*z % 8 == 0 (bijective chunked XCD remap).
template <int BM, int BN, int NW, bool BF16OUT, bool DBUF>
__global__ __launch_bounds__(NW * 64, NW == 4 ? 4 : 2) void gemmk(
    const unsigned short* __restrict__ A, int lda, size_t aBatch,
    const unsigned short* __restrict__ Bm, int ldb, size_t bBatch,
    void* __restrict__ Cout, int ldc, size_t cBatch,
    const float* __restrict__ bias, int K) {
  constexpr int NWC = BN / 64;          // n-waves
  constexpr int MI = 4, NI = 4;         // 64x64 wave tile
  constexpr int ACHA = BM / 8 / NW;     // A staging chunks per wave
  constexpr int ACHB = BN / 8 / NW;     // B staging chunks per wave
  constexpr int NS = DBUF ? 2 : 1;
  __shared__ unsigned short lds[NS][(BM + BN) * 64];
  const int tid = threadIdx.x;
  const int lane = tid & 63, w = tid >> 6;

  // ---- bijective chunked XCD remap, x-fastest decode ----
  const int gx = gridDim.x, gy = gridDim.y;
  int lid = blockIdx.x + gx * (blockIdx.y + gy * blockIdx.z);
  const int nwg = gx * gy * (int)gridDim.z;
  const int qch = nwg >> 3;
  lid = (lid & 7) * qch + (lid >> 3);
  const int bx = lid % gx;
  const int rem = lid / gx;
  const int by = rem % gy;
  const int bz = rem / gy;

  const int m0 = by * BM, n0 = bx * BN;
  const unsigned short* Aptr = A + (size_t)bz * aBatch;
  const unsigned short* Bptr = Bm + (size_t)bz * bBatch;

  const int lr = lane >> 3, lc = lane & 7;
  const int csw = (lc ^ lr) << 3;  // inverse-swizzled source col (elems)
  const int wr = w / NWC, wc = w % NWC;
  const int fr = lane & 15, fk = lane >> 4;
  const int nt = K >> 6;  // 12

  f32x4 acc[MI][NI] = {};

  auto stage = [&](int t, int s) {
    const int k0 = t << 6;
#pragma unroll
    for (int l = 0; l < ACHA; ++l) {
      const int c = w * ACHA + l;
      GLDS16(Aptr + (size_t)(m0 + c * 8 + lr) * lda + k0 + csw,
             &lds[s][c * 512]);
    }
#pragma unroll
    for (int l = 0; l < ACHB; ++l) {
      const int c = w * ACHB + l;
      GLDS16(Bptr + (size_t)(n0 + c * 8 + lr) * ldb + k0 + csw,
             &lds[s][BM * 64 + c * 512]);
    }
  };

  auto compute = [&](int s) {
#pragma unroll
    for (int ks = 0; ks < 2; ++ks) {
      bf16x8 af[MI], bf[NI];
#pragma unroll
      for (int mi = 0; mi < MI; ++mi) {
        const int row = wr * 64 + mi * 16 + fr;
        af[mi] = *(const bf16x8*)&lds[s][row * 64 +
                                         ((ks * 32 + fk * 8) ^
                                          ((row & 7) << 3))];
      }
#pragma unroll
      for (int ni = 0; ni < NI; ++ni) {
        const int row = wc * 64 + ni * 16 + fr;
        bf[ni] = *(const bf16x8*)&lds[s][BM * 64 + row * 64 +
                                         ((ks * 32 + fk * 8) ^
                                          ((row & 7) << 3))];
      }
      __builtin_amdgcn_s_setprio(1);
#pragma unroll
      for (int mi = 0; mi < MI; ++mi)
#pragma unroll
        for (int ni = 0; ni < NI; ++ni)
          acc[mi][ni] = __builtin_amdgcn_mfma_f32_16x16x32_bf16(
              af[mi], bf[ni], acc[mi][ni], 0, 0, 0);
      __builtin_amdgcn_s_setprio(0);
    }
  };

  if constexpr (DBUF) {
    stage(0, 0);
    __syncthreads();  // slot 0 resident
    for (int t = 0; t < nt; ++t) {
      const int s = t & 1;
      if (t + 1 < nt) stage(t + 1, s ^ 1);  // async prefetch, other slot
      compute(s);
      __syncthreads();  // drains prefetch; all reads of slot s done
    }
  } else {
    for (int t = 0; t < nt; ++t) {
      stage(t, 0);
      __syncthreads();  // tile resident
      compute(0);
      __syncthreads();  // reads done before next stage overwrites
    }
  }

  // ---- epilogue ----
#pragma unroll
  for (int mi = 0; mi < MI; ++mi) {
#pragma unroll
    for (int ni = 0; ni < NI; ++ni) {
      const int col = n0 + wc * 64 + ni * 16 + fr;
      float bv = 0.0f;
      if (!BF16OUT) bv = bias[col];
#pragma unroll
      for (int r = 0; r < 4; ++r) {
        const int row = m0 + wr * 64 + mi * 16 + fk * 4 + r;
        const float val = acc[mi][ni][r] + bv;
        if (BF16OUT)
          ((unsigned short*)Cout + (size_t)bz * cBatch)
              [(size_t)row * ldc + col] = f2bf(val);
        else
          ((float*)Cout + (size_t)bz * cBatch)
              [(size_t)row * ldc + col] = val;
      }
    }
  }
}

// -------- kTv partials: part[c][bh][e][d] = sum_{j in chunk c} v*k ------
// grid (chunk=8, bh=96), 256 threads. No atomics: each block owns its slab.
__global__ __launch_bounds__(256) void ktv_kernel(
    const unsigned short* __restrict__ qkv, float* __restrict__ part) {
  __shared__ unsigned short kls[128 * 64];
  __shared__ unsigned short vls[128 * 64];
  const int bh = blockIdx.y;
  const int bb = bh / Hh, h = bh % Hh;
  const int chunk = blockIdx.x;
  const int j0 = chunk * 128;
  const int tid = threadIdx.x, lane = tid & 63, w = tid >> 6;
  const size_t rowbase = (size_t)(bb * Nn + j0);
#pragma unroll
  for (int i = 0; i < 4; ++i) {
    const int c = w * 4 + i;
    const int row = c * 8 + (lane >> 3);
    const int col = (lane & 7) * 8;
    const size_t g = (rowbase + row) * QKVN + h * HDd + col;
    GLDS16(qkv + g + Dd, &kls[c * 512]);       // k slice
    GLDS16(qkv + g + 2 * Dd, &vls[c * 512]);   // v slice
  }
  asm volatile("s_waitcnt vmcnt(0)" ::: "memory");
  __syncthreads();

  const int e0 = (tid >> 4) * 4, d0 = (tid & 15) * 4;
  float acc[4][4] = {};
#pragma unroll 4
  for (int j = 0; j < 128; ++j) {
    const ushort4 kv = *(const ushort4*)&kls[j * 64 + d0];
    const ushort4 vv = *(const ushort4*)&vls[j * 64 + e0];
    const float kf[4] = {bf2f(kv.x), bf2f(kv.y), bf2f(kv.z), bf2f(kv.w)};
    const float vf[4] = {bf2f(vv.x), bf2f(vv.y), bf2f(vv.z), bf2f(vv.w)};
#pragma unroll
    for (int e = 0; e < 4; ++e)
#pragma unroll
      for (int d = 0; d < 4; ++d) acc[e][d] += vf[e] * kf[d];
  }
  float* outp = part + ((size_t)chunk * 96 + bh) * 4096;
#pragma unroll
  for (int e = 0; e < 4; ++e)
#pragma unroll
    for (int d = 0; d < 4; ++d)
      outp[(e0 + e) * HDd + (d0 + d)] = acc[e][d];
}

// ------- kfin[bh][e][d] = bf16(SCALE * sum_c part[c][bh][e][d]) --------
__global__ __launch_bounds__(256) void kfin_kernel(
    const float* __restrict__ part, unsigned short* __restrict__ kfin) {
  const int bh = blockIdx.x, tid = threadIdx.x;
  const float* kp = part + (size_t)bh * 4096;
  unsigned short* op = kfin + (size_t)bh * 4096;
  for (int i = tid * 4; i < 4096; i += 1024) {
    float4 s = {0.f, 0.f, 0.f, 0.f};
#pragma unroll
    for (int cc = 0; cc < 8; ++cc) {
      const float4 v = *(const float4*)&kp[(size_t)cc * 96 * 4096 + i];
      s.x += v.x; s.y += v.y; s.z += v.z; s.w += v.w;
    }
    ushort4 o;
    o.x = f2bf(s.x * SCALE_F); o.y = f2bf(s.y * SCALE_F);
    o.z = f2bf(s.z * SCALE_F); o.w = f2bf(s.w * SCALE_F);
    *(ushort4*)&op[i] = o;
  }
}

// ---- attn_out: ao[b,j,h*64+e] = sum_d q[b,j,h,d] * kfin[bh][e][d] -----
// Writes into qkv's dead v-slice (cols 1536..2303). grid (jt=8, bh=96).
// A=q staged with the proven XOR-swizzle path; B=kfin in padded LDS.
__global__ __launch_bounds__(256) void attn_out_kernel(
    unsigned short* qkv, const unsigned short* __restrict__ kfin) {
  __shared__ unsigned short qls[128 * 64];
  __shared__ unsigned short bs[64 * 72];  // [e][d], pad 72 (2-way = free)
  const int bh = blockIdx.y;
  const int bb = bh / Hh, h = bh % Hh;
  const int jt = blockIdx.x;
  const int tid = threadIdx.x, lane = tid & 63, w = tid >> 6;
  const int lr = lane >> 3, lc = lane & 7;
  const int csw = (lc ^ lr) << 3;
  const size_t rowbase = (size_t)(bb * Nn + jt * 128);
#pragma unroll
  for (int l = 0; l < 4; ++l) {
    const int c = w * 4 + l;
    GLDS16(qkv + (rowbase + c * 8 + lr) * QKVN + h * HDd + csw,
           &qls[c * 512]);
  }
  for (int i = tid * 8; i < 4096; i += 2048) {
    const int e = i >> 6, d = i & 63;
    *(bf16x8*)&bs[e * 72 + d] = *(const bf16x8*)&kfin[(size_t)bh * 4096 + i];
  }
  asm volatile("s_waitcnt vmcnt(0)" ::: "memory");
  __syncthreads();

  const int fr = lane & 15, fk = lane >> 4;
  f32x4 acc[2][4] = {};
#pragma unroll
  for (int ks = 0; ks < 2; ++ks) {
    bf16x8 af[2];
#pragma unroll
    for (int mi = 0; mi < 2; ++mi) {
      const int row = w * 32 + mi * 16 + fr;
      af[mi] = *(const bf16x8*)&qls[row * 64 +
                                    ((ks * 32 + fk * 8) ^ ((row & 7) << 3))];
    }
#pragma unroll
    for (int ni = 0; ni < 4; ++ni) {
      const bf16x8 bfr =
          *(const bf16x8*)&bs[(ni * 16 + fr) * 72 + ks * 32 + fk * 8];
#pragma unroll
      for (int mi = 0; mi < 2; ++mi)
        acc[mi][ni] = __builtin_amdgcn_mfma_f32_16x16x32_bf16(
            af[mi], bfr, acc[mi][ni], 0, 0, 0);
    }
  }
#pragma unroll
  for (int mi = 0; mi < 2; ++mi)
#pragma unroll
    for (int ni = 0; ni < 4; ++ni)
#pragma unroll
      for (int r = 0; r < 4; ++r) {
        const int row = jt * 128 + w * 32 + mi * 16 + fk * 4 + r;
        const int col = ni * 16 + fr;
        qkv[((size_t)bb * Nn + row) * QKVN + 2 * Dd + h * HDd + col] =
            f2bf(acc[mi][ni][r]);
      }
}

extern "C" void kernel_launch(void* const* d_in, const int* in_sizes, int n_in,
                              void* d_out, int out_size, void* d_ws,
                              size_t ws_size, hipStream_t stream) {
  const float* x = (const float*)d_in[0];
  const float* wqkv = (const float*)d_in[1];
  const float* wfc = (const float*)d_in[2];
  const float* bfc = (const float*)d_in[3];
  float* out = (float*)d_out;

  char* ws = (char*)d_ws;
  unsigned short* xb    = (unsigned short*)(ws);                // 12.6 MB
  float*          part  = (float*)(ws);      // aliases xb (dead after gemm1)
  unsigned short* wqkvb = (unsigned short*)(ws + 12582912);     // 3.5 MB
  unsigned short* wfcb  = (unsigned short*)(ws + 16121856);     // 1.2 MB
  unsigned short* qkv   = (unsigned short*)(ws + 17301504);     // 37.7 MB
  unsigned short* kfin  = (unsigned short*)(ws + 55050240);     // 0.79 MB
  // total used: 55,836,672 bytes

  convert_kernel<<<2112, 256, 0, stream>>>(x, wqkv, wfc, xb, wqkvb, wfcb);
  // qkv = x * wqkv^T : M=8192, N=2304, K=768  (grid 18*64 = 1152, %8==0)
  // single-buffer 4-wave 128x128 — measured best across nine variants
  gemmk<128, 128, 4, true, false>
      <<<dim3(QKVN / 128, Mm / 128, 1), 256, 0, stream>>>(
          xb, Dd, 0, wqkvb, Dd, 0, qkv, QKVN, 0, nullptr, Dd);
  // part[c][bh] = per-chunk K^T V partials (xb is dead; reuse its space)
  ktv_kernel<<<dim3(8, 96), 256, 0, stream>>>(qkv, part);
  // kfin = bf16(SCALE * sum_c part)
  kfin_kernel<<<96, 256, 0, stream>>>(part, kfin);
  // attn_out: q x kfin -> overwrite qkv's dead v-slice
  attn_out_kernel<<<dim3(8, 96), 256, 0, stream>>>(qkv, kfin);
  // out = ao * wfc^T + bias : M=8192, N=768, K=768, SHARED weights
  // (grid 6*64 = 384, %8==0) — R15-proven DBUF 4-wave config
  gemmk<128, 128, 4, false, true>
      <<<dim3(Dd / 128, Mm / 128, 1), 256, 0, stream>>>(
          qkv + 2 * Dd, QKVN, 0, wfcb, Dd, 0, out, Dd, 0, bfc, Dd);
}